// Round 4
// baseline (625.660 us; speedup 1.0000x reference)
//
#include <hip/hip_runtime.h>
#include <hip/hip_bf16.h>
#include <hip/hip_fp16.h>

// RelMultiHeadDotProductAttention (Transformer-XL rel attention)
// B=2 S=2048 D=1024 H=16 Dh=64 F=1024. fp32 in/out; internal bf16 MFMA.
// Round 10: occupancy push. R9 was latency-bound (MfmaUtil 10%, VALU 28%,
// HBM 2%, occ 45% = 2 WG/CU; nothing busy). New wave decomposition (th,w2):
// each wave owns one q-HALF (16 q) x one k-share -> Q-frags 32->16 regs,
// acc 32->16 regs (~60-70 total). KC 512->256 halves score dbuf: LDS
// 66->33.9 KB/WG. Both caps lifted: 3-4 WG/CU co-resident. Work/wave
// unchanged; K/R/V loads duplicated x2 across th-pairs (L1/L2 absorbed).
// Single-pass tail (wave's 16qx64dh partials = 32 KB fits buffer).
// __launch_bounds__(512,6): reg cap 85 -> no spill risk (R7/R8 lesson).

#define B_  2
#define S_  2048
#define D_  1024
#define H_  16
#define DH_ 64
#define HD_ 1024
#define F_  1024
#define N_  4096   // B*S
#define KC_ 256    // k-chunk
#define NCH 8      // chunks
#define SP2 260    // chunk row stride (fp16): 130 dw = 2 mod 32 banks
#define KQSC 0.1803368801111204f  // log2(e)/8, folded into qw/qr at GEMM epilogue

typedef __attribute__((ext_vector_type(8))) short  short8;   // 8 x bf16 (4 VGPRs)
typedef __attribute__((ext_vector_type(4))) float  floatx4;
typedef __attribute__((ext_vector_type(4))) unsigned int uintx4;

__device__ __forceinline__ unsigned short f2bf(float x) {
  unsigned u = __float_as_uint(x);
  u += 0x7FFFu + ((u >> 16) & 1u);          // RNE
  return (unsigned short)(u >> 16);
}
__device__ __forceinline__ unsigned short f2h(float x) {
  __half h = __float2half(x);
  unsigned short u; __builtin_memcpy(&u, &h, 2);
  return u;
}
__device__ __forceinline__ float h2f(unsigned short u) {
  __half h; __builtin_memcpy(&h, &u, 2);
  return __half2float(h);
}

// ------------- cast fp32 -> bf16: all three activations in one launch -------------
#define CQ_ (N_ * D_ / 4)   // 1048576 float4 units each for q, kv
__global__ void cast_all(const float* __restrict__ sq, const float* __restrict__ skv,
                         const float* __restrict__ spos,
                         unsigned short* __restrict__ dq, unsigned short* __restrict__ dkv,
                         unsigned short* __restrict__ dpos) {
  int i = blockIdx.x * blockDim.x + threadIdx.x;
  const float* s; unsigned short* d; int off;
  if (i < CQ_)            { s = sq;   d = dq;   off = i; }
  else if (i < 2 * CQ_)   { s = skv;  d = dkv;  off = i - CQ_; }
  else                    { s = spos; d = dpos; off = i - 2 * CQ_; }
  float4 v = ((const float4*)s)[off];
  ushort4 o = make_ushort4(f2bf(v.x), f2bf(v.y), f2bf(v.z), f2bf(v.w));
  ((ushort4*)d)[off] = o;
}

// ---------- cast + transpose 1024x1024 weights (all 5 in one launch, z picks) ----------
struct TP5 { const float* s[5]; unsigned short* d[5]; };
__global__ void transpose_all(TP5 p) {
  __shared__ float t[32][33];
  const float* src = p.s[blockIdx.z];
  unsigned short* dst = p.d[blockIdx.z];
  int c0 = blockIdx.x * 32, r0 = blockIdx.y * 32;
  int tx = threadIdx.x, ty = threadIdx.y;   // (32,8)
#pragma unroll
  for (int i = 0; i < 4; i++)
    t[ty + i * 8][tx] = src[(size_t)(r0 + ty + i * 8) * 1024 + c0 + tx];
  __syncthreads();
#pragma unroll
  for (int i = 0; i < 4; i++)
    dst[(size_t)(c0 + ty + i * 8) * 1024 + r0 + tx] = f2bf(t[tx][ty + i * 8]);
}

// ---------------- bf16 GEMM, C = A[M][K] * Bt[N][K]^T + bias ----------------
// 4-segment dispatch: block bx picks segment by bend boundaries (monotone).
// mode 0: outA bf16 = acc + bias
// mode 1: outA bf16 = (acc+bias+b2a)*KQSC ; outB bf16 = (acc+bias+b2b)*KQSC
// mode 2: outF fp32 = acc + bias
// mode 4: bf16, written directly in vt layout [b][h][dh][s]
struct GSeg {
  const unsigned short* A; const unsigned short* Bt;
  const float* bias; const float* b2a; const float* b2b;
  unsigned short* outA; unsigned short* outB; float* outF;
  int mode; int bend;
};
struct GP { GSeg s[4]; };
__launch_bounds__(256, 2)
__global__ void gemm_bt(GP p, int Nn, int K) {
  __shared__ unsigned short As[128 * 64];
  __shared__ unsigned short Bs[128 * 64];
  int bx = blockIdx.x;
  GSeg g = p.s[0]; int base = 0;
  if (bx >= p.s[0].bend) { g = p.s[1]; base = p.s[0].bend; }
  if (bx >= p.s[1].bend) { g = p.s[2]; base = p.s[1].bend; }
  if (bx >= p.s[2].bend) { g = p.s[3]; base = p.s[2].bend; }
  bx -= base;
  int nb = Nn >> 7;
  int bm = bx / nb, bn = bx % nb;
  int tid = threadIdx.x;
  int lane = tid & 63, wv = tid >> 6;
  int wm = wv >> 1, wn = wv & 1;
  int lm = lane & 15, lg = lane >> 4;
  const unsigned short* Ab = g.A + (size_t)(bm * 128) * K;
  const unsigned short* Bb = g.Bt + (size_t)(bn * 128) * K;
  floatx4 acc[4][4];
#pragma unroll
  for (int i = 0; i < 4; i++)
#pragma unroll
    for (int j = 0; j < 4; j++) acc[i][j] = (floatx4){0.f, 0.f, 0.f, 0.f};

  int lr = tid >> 3;          // 0..31 staging row
  int lc = (tid & 7) * 8;     // staging col (8 bf16 = 16B)
  for (int k0 = 0; k0 < K; k0 += 64) {
    __syncthreads();
#pragma unroll
    for (int i = 0; i < 4; i++) {
      int r = i * 32 + lr;
      *(uint4*)&As[r * 64 + lc] = *(const uint4*)&Ab[(size_t)r * K + k0 + lc];
      *(uint4*)&Bs[r * 64 + lc] = *(const uint4*)&Bb[(size_t)r * K + k0 + lc];
    }
    __syncthreads();
#pragma unroll
    for (int kk = 0; kk < 2; kk++) {
      short8 af[4], bf[4];
#pragma unroll
      for (int i = 0; i < 4; i++)
        af[i] = *(const short8*)&As[(wm * 64 + i * 16 + lm) * 64 + kk * 32 + lg * 8];
#pragma unroll
      for (int j = 0; j < 4; j++)
        bf[j] = *(const short8*)&Bs[(wn * 64 + j * 16 + lm) * 64 + kk * 32 + lg * 8];
#pragma unroll
      for (int i = 0; i < 4; i++)
#pragma unroll
        for (int j = 0; j < 4; j++)
          acc[i][j] = __builtin_amdgcn_mfma_f32_16x16x32_bf16(af[i], bf[j], acc[i][j], 0, 0, 0);
    }
  }
  // epilogue: C/D layout col=lane&15, row=(lane>>4)*4+reg  [m89/m91 verified]
#pragma unroll
  for (int j = 0; j < 4; j++) {
    int col = bn * 128 + wn * 64 + j * 16 + lm;
    float bs = g.bias ? g.bias[col] : 0.f;
    float ba = g.b2a ? g.b2a[col] : 0.f;
    float bb = g.b2b ? g.b2b[col] : 0.f;
#pragma unroll
    for (int i = 0; i < 4; i++) {
      int row0 = bm * 128 + wm * 64 + i * 16 + lg * 4;
      if (g.mode == 4) {
        // vt[b][h][dh][s]: 4 consecutive s -> vector store
        int s = row0 & 2047, bb2 = row0 >> 11;
        size_t vidx = (((size_t)bb2 * H_ + (col >> 6)) * 64 + (col & 63)) * (size_t)S_ + s;
        ushort4 o = make_ushort4(f2bf(acc[i][j][0] + bs), f2bf(acc[i][j][1] + bs),
                                 f2bf(acc[i][j][2] + bs), f2bf(acc[i][j][3] + bs));
        *(ushort4*)&g.outA[vidx] = o;
      } else {
#pragma unroll
        for (int r = 0; r < 4; r++) {
          float v = acc[i][j][r] + bs;
          size_t idx = (size_t)(row0 + r) * Nn + col;
          if (g.mode == 0)      g.outA[idx] = f2bf(v);
          else if (g.mode == 1) { g.outA[idx] = f2bf((v + ba) * KQSC); g.outB[idx] = f2bf((v + bb) * KQSC); }
          else                  g.outF[idx] = v;
        }
      }
    }
  }
}

// ---------------- fused rel-attention per (b, h, 32-query tile) ----------------
// 512 threads = 8 waves; wave (w2 = wv>>1, th = wv&1) owns q-half th (16 q)
// x k-share [w2*64, w2*64+64) of each 256-chunk. ~33.9 KiB LDS -> 3-4 WG/CU.
// Per chunk c (8 chunks of 256):
//   A(c): R^T tiles jt = w2,w2+4,..<18 for q-half th; scatter fp16 into dbuf
//   B'(c): 4 kt tiles: K.Qw^T MFMA, +R, exp2, sum (reg), P bf16 in place
//   D(c): O += P V, 2 slices of 32 (own rows/cols; no barrier after B')
// One barrier per chunk. K/R/V loads duplicated across th-pairs (L1/L2 hits).
// Tail: 4-way k-share sum/O reduce per q-half; single pass (32 KB in sS).
__launch_bounds__(512, 6)
__global__ void attn_kernel(const unsigned short* __restrict__ qw,
                            const unsigned short* __restrict__ qr,
                            const unsigned short* __restrict__ kb,
                            const unsigned short* __restrict__ rb,
                            const unsigned short* __restrict__ vt,
                            unsigned short* __restrict__ xb) {
  __shared__ __align__(16) unsigned short sS[2][32 * SP2];  // dbuf score chunks (33.3 KB)
  __shared__ float sSum[8][16];
  __shared__ float sLinv[32];
  int bid = blockIdx.x;                 // 2048 = 32 bh * 64 qt
  int l = ((bid & 7) << 8) | (bid >> 3);  // XCD swizzle: xcd gets 4 whole bh
  int qt = l & 63;
  int bh = l >> 6;
  int b = bh >> 4, h = bh & 15;
  int q0 = qt * 32;
  int tid = threadIdx.x;
  int lane = tid & 63, wv = tid >> 6;   // wv 0..7
  int lm = lane & 15, lg = lane >> 4;
  int th = wv & 1, w2 = wv >> 1;        // q-half / k-share index

  // Q frags for OWN q-half only (pre-scaled by log2(e)/8 in GEMM): 16 regs
  const size_t qbase = (size_t)(b * S_ + q0 + th * 16 + lm) * HD_ + h * 64 + lg * 8;
  short8 bqw0 = *(const short8*)(qw + qbase);
  short8 bqw1 = *(const short8*)(qw + qbase + 32);
  short8 bqr0 = *(const short8*)(qr + qbase);
  short8 bqr1 = *(const short8*)(qr + qbase + 32);

  floatx4 acc[4];                       // O accumulator: own 16q x 64dh share
#pragma unroll
  for (int j = 0; j < 4; j++) acc[j] = (floatx4){0.f, 0.f, 0.f, 0.f};
  float s0 = 0.f;                       // exp-sum accumulator (own q-half)

  const unsigned short* vb0 = vt + (size_t)(b * H_ + h) * 64 * S_;

  for (int c = 0; c < NCH; c++) {
    unsigned short* S = sS[c & 1];
    int kc = c * KC_;
    // ---- A(c): R scatter, q-half th, tiles jt = w2, w2+4, ... < 18 ----
    for (int jt = w2; jt < 18; jt += 4) {
      int jrow = (kc - q0 - 32 + jt * 16 + lm) & 2047;
      const unsigned short* rp = rb + (size_t)jrow * HD_ + h * 64 + lg * 8;
      short8 a0 = *(const short8*)(rp);
      short8 a1 = *(const short8*)(rp + 32);
      floatx4 c4 = (floatx4){0.f, 0.f, 0.f, 0.f};
      c4 = __builtin_amdgcn_mfma_f32_16x16x32_bf16(a0, bqr0, c4, 0, 0, 0);
      c4 = __builtin_amdgcn_mfma_f32_16x16x32_bf16(a1, bqr1, c4, 0, 0, 0);
      int q = th * 16 + lm;
      int ub = jt * 16 + lg * 4 + q - 31;   // u = k - kc for this lane's rows
      unsigned short* row = &S[q * SP2];
      if (jt + th >= 2 && jt + th <= 16) {  // wave-uniform: all 64 lanes in-range
#pragma unroll
        for (int r = 0; r < 4; r++) row[ub + r] = f2h(c4[r]);
      } else {
#pragma unroll
        for (int r = 0; r < 4; r++) {
          int u = ub + r;
          if ((unsigned)u < (unsigned)KC_) row[u] = f2h(c4[r]);
        }
      }
    }
    __syncthreads();                    // the only barrier in the chunk loop
    // ---- B'(c): content + R + exp2 + sum + write P (own rows/cols) ----
#pragma unroll
    for (int kt = 0; kt < 4; kt++) {
      int u0 = w2 * 64 + kt * 16;
      const unsigned short* kp = kb + (size_t)(b * S_ + kc + u0 + lm) * HD_ + h * 64 + lg * 8;
      short8 a0 = *(const short8*)(kp);
      short8 a1 = *(const short8*)(kp + 32);
      floatx4 c4 = (floatx4){0.f, 0.f, 0.f, 0.f};
      c4 = __builtin_amdgcn_mfma_f32_16x16x32_bf16(a0, bqw0, c4, 0, 0, 0);
      c4 = __builtin_amdgcn_mfma_f32_16x16x32_bf16(a1, bqw1, c4, 0, 0, 0);
      int q = th * 16 + lm;
      unsigned short* pp = &S[q * SP2 + u0 + lg * 4];
      ushort4 Rv = *(const ushort4*)pp;
      float p0 = exp2f(c4[0] + h2f(Rv.x));
      float p1 = exp2f(c4[1] + h2f(Rv.y));
      float p2 = exp2f(c4[2] + h2f(Rv.z));
      float p3 = exp2f(c4[3] + h2f(Rv.w));
      s0 += (p0 + p1) + (p2 + p3);
      unsigned w0, w1;
      asm("v_cvt_pk_bf16_f32 %0, %1, %2" : "=v"(w0) : "v"(p0), "v"(p1));
      asm("v_cvt_pk_bf16_f32 %0, %1, %2" : "=v"(w1) : "v"(p2), "v"(p3));
      *(uint2*)pp = make_uint2(w0, w1);
    }
    // ---- D(c): O += P V (own q rows, own k cols; no barrier after B').
    //      P reads as 2x b64: dw-stride 130 = 2 mod 32 -> uniform banks. ----
#pragma unroll
    for (int s = 0; s < 2; s++) {
      int u0 = w2 * 64 + s * 32;
      int e0 = (th * 16 + lm) * SP2 + u0 + lg * 8;
      uint2 x0 = *(const uint2*)&S[e0];
      uint2 x1 = *(const uint2*)&S[e0 + 4];
      uintx4 ua = {x0.x, x0.y, x1.x, x1.y};
      short8 a0 = __builtin_bit_cast(short8, ua);
      const unsigned short* vp = vb0 + kc + u0 + lg * 8;
#pragma unroll
      for (int j = 0; j < 4; j++) {
        short8 bb = *(const short8*)&vp[(size_t)(j * 16 + lm) * S_];
        acc[j] = __builtin_amdgcn_mfma_f32_16x16x32_bf16(a0, bb, acc[j], 0, 0, 0);
      }
    }
  }
  // ---- tail: in-wave sum reduce over lg, then 4-way k-share reduce ----
  s0 += __shfl_xor(s0, 16); s0 += __shfl_xor(s0, 32);
  if (lane < 16) sSum[wv][lane] = s0;   // q = th*16+lane, share w2
  __syncthreads();                      // also: all D(7) P-reads done -> sS dead
  if (tid < 32) {
    float t = 0.f;
#pragma unroll
    for (int i = 0; i < 4; i++) t += sSum[2 * i + (tid >> 4)][tid & 15];
    sLinv[tid] = 1.f / t;
  }
  float* po = (float*)sS;               // 8 waves x 16q x 64dh f32 = 32 KiB
#pragma unroll
  for (int j = 0; j < 4; j++)
#pragma unroll
    for (int r = 0; r < 4; r++)
      po[wv * 1024 + (lg * 4 + r) * 64 + j * 16 + lm] = acc[j][r];
  __syncthreads();
  {
    int e = tid * 4;                    // 512 threads x 4 = 2048 outputs
    int q = e >> 6, dh = e & 63;
    int th2 = q >> 4, lq = q & 15;
    float4 v = *(float4*)&po[th2 * 1024 + lq * 64 + dh];
#pragma unroll
    for (int i = 1; i < 4; i++) {
      float4 u = *(float4*)&po[(2 * i + th2) * 1024 + lq * 64 + dh];
      v.x += u.x; v.y += u.y; v.z += u.z; v.w += u.w;
    }
    float li = sLinv[q];
    ushort4 o = make_ushort4(f2bf(v.x * li), f2bf(v.y * li), f2bf(v.z * li), f2bf(v.w * li));
    *(ushort4*)&xb[(size_t)(b * S_ + q0 + q) * HD_ + h * 64 + dh] = o;
  }
}

extern "C" void kernel_launch(void* const* d_in, const int* in_sizes, int n_in,
                              void* d_out, int out_size, void* d_ws, size_t ws_size,
                              hipStream_t stream) {
  const float* inputs_q  = (const float*)d_in[0];
  const float* inputs_kv = (const float*)d_in[1];
  const float* pos_embed = (const float*)d_in[2];
  const float* Wq   = (const float*)d_in[3];
  const float* bq   = (const float*)d_in[4];
  const float* Wk   = (const float*)d_in[5];
  const float* bk   = (const float*)d_in[6];
  const float* Wv   = (const float*)d_in[7];
  const float* bv   = (const float*)d_in[8];
  const float* Wpos = (const float*)d_in[9];
  const float* rrb  = (const float*)d_in[10];
  const float* rwb  = (const float*)d_in[11];
  const float* Wout = (const float*)d_in[12];
  const float* bout = (const float*)d_in[13];
  float* out = (float*)d_out;

  char* ws = (char*)d_ws;                       // ~66 MB used
  unsigned short* aq  = (unsigned short*)(ws);                 // 8MB (reused as xb)
  unsigned short* akv = (unsigned short*)(ws + ( 8u << 20));   // 8MB
  unsigned short* apo = (unsigned short*)(ws + (16u << 20));   // 4MB
  unsigned short* wqt = (unsigned short*)(ws + (20u << 20));   // 2MB each
  unsigned short* wkt = (unsigned short*)(ws + (22u << 20));
  unsigned short* wvt = (unsigned short*)(ws + (24u << 20));
  unsigned short* wpt = (unsigned short*)(ws + (26u << 20));
  unsigned short* wot = (unsigned short*)(ws + (28u << 20));
  unsigned short* qwp = (unsigned short*)(ws + (30u << 20));   // 8MB
  unsigned short* qrp = (unsigned short*)(ws + (38u << 20));   // 8MB
  unsigned short* kbp = (unsigned short*)(ws + (46u << 20));   // 8MB
  unsigned short* vtp = (unsigned short*)(ws + (54u << 20));   // 8MB (vt layout)
  unsigned short* rbp = (unsigned short*)(ws + (62u << 20));   // 4MB
  unsigned short* xbp = aq;                                    // aq dead after q-GEMM

  cast_all<<<10240, 256, 0, stream>>>(inputs_q, inputs_kv, pos_embed, aq, akv, apo);
  TP5 tp;
  tp.s[0] = Wq; tp.s[1] = Wk; tp.s[2] = Wv; tp.s[3] = Wpos; tp.s[4] = Wout;
  tp.d[0] = wqt; tp.d[1] = wkt; tp.d[2] = wvt; tp.d[3] = wpt; tp.d[4] = wot;
  transpose_all<<<dim3(32, 32, 5), dim3(32, 8), 0, stream>>>(tp);

  // all 4 projection GEMMs in ONE 896-block launch:
  //   [0,256): q dual-bias mode1 -> qwp/qrp   [256,384): rpos mode0 -> rbp
  //   [384,640): k mode0 -> kbp               [640,896): v mode4 -> vtp
  GP gp{};
  gp.s[0] = {aq,  wqt, bq,      rwb,     rrb,     qwp,     qrp,     nullptr, 1, 256};
  gp.s[1] = {apo, wpt, nullptr, nullptr, nullptr, rbp,     nullptr, nullptr, 0, 384};
  gp.s[2] = {akv, wkt, bk,      nullptr, nullptr, kbp,     nullptr, nullptr, 0, 640};
  gp.s[3] = {akv, wvt, bv,      nullptr, nullptr, vtp,     nullptr, nullptr, 4, 896};
  gemm_bt<<<896, 256, 0, stream>>>(gp, HD_, D_);

  attn_kernel<<<2048, 512, 0, stream>>>(qwp, qrp, kbp, rbp, vtp, xbp);

  GP go{};
  go.s[0] = {xbp, wot, bout, nullptr, nullptr, nullptr, nullptr, out, 2, 256};
  go.s[1] = {nullptr, nullptr, nullptr, nullptr, nullptr, nullptr, nullptr, nullptr, 0, 1 << 30};
  go.s[2] = go.s[1];
  go.s[3] = go.s[1];
  gemm_bt<<<256, 256, 0, stream>>>(go, F_, HD_);
}

// Round 5
// 540.883 us; speedup vs baseline: 1.1567x; 1.1567x over previous
//
#include <hip/hip_runtime.h>
#include <hip/hip_bf16.h>
#include <hip/hip_fp16.h>

// RelMultiHeadDotProductAttention (Transformer-XL rel attention)
// B=2 S=2048 D=1024 H=16 Dh=64 F=1024. fp32 in/out; internal bf16 MFMA.
// Round 11: revert R10's th-split (halved work per load -> 2x slower). Back to
// R9 structure (211us attn) + latency attack within the 128-reg budget (R9 used
// only 64): (1) B' K-frags kt0/1 prefetched PRE-barrier (latency covered by
// A-phase + barrier wait), kt2/3 issued immediately after; B' fully unrolled
// (was unroll 2). (2) A-phase R-loop software-pipelined 1-deep. (3) D batches
// all 8 V-loads + 4 P-LDS-reads ahead of a pure 16-MFMA cluster under s_setprio
// (m191: attn +4-7%). (4) cast+transpose merged into one prep launch.
// Spill check: WRITE_SIZE must stay ~8.2MB.

#define B_  2
#define S_  2048
#define D_  1024
#define H_  16
#define DH_ 64
#define HD_ 1024
#define F_  1024
#define N_  4096   // B*S
#define KC_ 512    // k-chunk
#define SP2 516    // chunk row stride (fp16): 258 dw = 2 mod 32 banks
#define KQSC 0.1803368801111204f  // log2(e)/8, folded into qw/qr at GEMM epilogue

typedef __attribute__((ext_vector_type(8))) short  short8;   // 8 x bf16 (4 VGPRs)
typedef __attribute__((ext_vector_type(4))) float  floatx4;
typedef __attribute__((ext_vector_type(4))) unsigned int uintx4;

__device__ __forceinline__ unsigned short f2bf(float x) {
  unsigned u = __float_as_uint(x);
  u += 0x7FFFu + ((u >> 16) & 1u);          // RNE
  return (unsigned short)(u >> 16);
}
__device__ __forceinline__ unsigned short f2h(float x) {
  __half h = __float2half(x);
  unsigned short u; __builtin_memcpy(&u, &h, 2);
  return u;
}
__device__ __forceinline__ float h2f(unsigned short u) {
  __half h; __builtin_memcpy(&h, &u, 2);
  return __half2float(h);
}

// ------- prep: fp32->bf16 casts (q, kv, pos) + 5 weight transposes, ONE launch -------
#define CQ_ (N_ * D_ / 4)   // 1048576 float4 units each for q, kv
#define CAST_BLKS 10240     // (2*CQ_ + S_*D_/4) / 256
struct PrepP {
  const float* sq; const float* skv; const float* spos;
  unsigned short* dq; unsigned short* dkv; unsigned short* dpos;
  const float* ts[5]; unsigned short* td[5];
};
__global__ void prep_all(PrepP p) {
  __shared__ float t[32][33];
  int bid = blockIdx.x;
  int tid = threadIdx.x;
  if (bid < CAST_BLKS) {
    int i = bid * 256 + tid;
    const float* s; unsigned short* d; int off;
    if (i < CQ_)            { s = p.sq;   d = p.dq;   off = i; }
    else if (i < 2 * CQ_)   { s = p.skv;  d = p.dkv;  off = i - CQ_; }
    else                    { s = p.spos; d = p.dpos; off = i - 2 * CQ_; }
    float4 v = ((const float4*)s)[off];
    ((ushort4*)d)[off] = make_ushort4(f2bf(v.x), f2bf(v.y), f2bf(v.z), f2bf(v.w));
  } else {
    int b2 = bid - CAST_BLKS;               // 0..5119: 5 matrices x 32x32 tiles
    int z = b2 >> 10, y = (b2 >> 5) & 31, x = b2 & 31;
    const float* src = p.ts[z];
    unsigned short* dst = p.td[z];
    int c0 = x * 32, r0 = y * 32;
    int tx = tid & 31, ty = tid >> 5;       // (32,8)
#pragma unroll
    for (int i = 0; i < 4; i++)
      t[ty + i * 8][tx] = src[(size_t)(r0 + ty + i * 8) * 1024 + c0 + tx];
    __syncthreads();
#pragma unroll
    for (int i = 0; i < 4; i++)
      dst[(size_t)(c0 + ty + i * 8) * 1024 + r0 + tx] = f2bf(t[tx][ty + i * 8]);
  }
}

// ---------------- bf16 GEMM, C = A[M][K] * Bt[N][K]^T + bias ----------------
// 4-segment dispatch: block bx picks segment by bend boundaries (monotone).
// mode 0: outA bf16 = acc + bias
// mode 1: outA bf16 = (acc+bias+b2a)*KQSC ; outB bf16 = (acc+bias+b2b)*KQSC
// mode 2: outF fp32 = acc + bias
// mode 4: bf16, written directly in vt layout [b][h][dh][s]
struct GSeg {
  const unsigned short* A; const unsigned short* Bt;
  const float* bias; const float* b2a; const float* b2b;
  unsigned short* outA; unsigned short* outB; float* outF;
  int mode; int bend;
};
struct GP { GSeg s[4]; };
__launch_bounds__(256, 2)
__global__ void gemm_bt(GP p, int Nn, int K) {
  __shared__ unsigned short As[128 * 64];
  __shared__ unsigned short Bs[128 * 64];
  int bx = blockIdx.x;
  GSeg g = p.s[0]; int base = 0;
  if (bx >= p.s[0].bend) { g = p.s[1]; base = p.s[0].bend; }
  if (bx >= p.s[1].bend) { g = p.s[2]; base = p.s[1].bend; }
  if (bx >= p.s[2].bend) { g = p.s[3]; base = p.s[2].bend; }
  bx -= base;
  int nb = Nn >> 7;
  int bm = bx / nb, bn = bx % nb;
  int tid = threadIdx.x;
  int lane = tid & 63, wv = tid >> 6;
  int wm = wv >> 1, wn = wv & 1;
  int lm = lane & 15, lg = lane >> 4;
  const unsigned short* Ab = g.A + (size_t)(bm * 128) * K;
  const unsigned short* Bb = g.Bt + (size_t)(bn * 128) * K;
  floatx4 acc[4][4];
#pragma unroll
  for (int i = 0; i < 4; i++)
#pragma unroll
    for (int j = 0; j < 4; j++) acc[i][j] = (floatx4){0.f, 0.f, 0.f, 0.f};

  int lr = tid >> 3;          // 0..31 staging row
  int lc = (tid & 7) * 8;     // staging col (8 bf16 = 16B)
  for (int k0 = 0; k0 < K; k0 += 64) {
    __syncthreads();
#pragma unroll
    for (int i = 0; i < 4; i++) {
      int r = i * 32 + lr;
      *(uint4*)&As[r * 64 + lc] = *(const uint4*)&Ab[(size_t)r * K + k0 + lc];
      *(uint4*)&Bs[r * 64 + lc] = *(const uint4*)&Bb[(size_t)r * K + k0 + lc];
    }
    __syncthreads();
#pragma unroll
    for (int kk = 0; kk < 2; kk++) {
      short8 af[4], bf[4];
#pragma unroll
      for (int i = 0; i < 4; i++)
        af[i] = *(const short8*)&As[(wm * 64 + i * 16 + lm) * 64 + kk * 32 + lg * 8];
#pragma unroll
      for (int j = 0; j < 4; j++)
        bf[j] = *(const short8*)&Bs[(wn * 64 + j * 16 + lm) * 64 + kk * 32 + lg * 8];
#pragma unroll
      for (int i = 0; i < 4; i++)
#pragma unroll
        for (int j = 0; j < 4; j++)
          acc[i][j] = __builtin_amdgcn_mfma_f32_16x16x32_bf16(af[i], bf[j], acc[i][j], 0, 0, 0);
    }
  }
  // epilogue: C/D layout col=lane&15, row=(lane>>4)*4+reg  [m89/m91 verified]
#pragma unroll
  for (int j = 0; j < 4; j++) {
    int col = bn * 128 + wn * 64 + j * 16 + lm;
    float bs = g.bias ? g.bias[col] : 0.f;
    float ba = g.b2a ? g.b2a[col] : 0.f;
    float bb = g.b2b ? g.b2b[col] : 0.f;
#pragma unroll
    for (int i = 0; i < 4; i++) {
      int row0 = bm * 128 + wm * 64 + i * 16 + lg * 4;
      if (g.mode == 4) {
        // vt[b][h][dh][s]: 4 consecutive s -> vector store
        int s = row0 & 2047, bb2 = row0 >> 11;
        size_t vidx = (((size_t)bb2 * H_ + (col >> 6)) * 64 + (col & 63)) * (size_t)S_ + s;
        ushort4 o = make_ushort4(f2bf(acc[i][j][0] + bs), f2bf(acc[i][j][1] + bs),
                                 f2bf(acc[i][j][2] + bs), f2bf(acc[i][j][3] + bs));
        *(ushort4*)&g.outA[vidx] = o;
      } else {
#pragma unroll
        for (int r = 0; r < 4; r++) {
          float v = acc[i][j][r] + bs;
          size_t idx = (size_t)(row0 + r) * Nn + col;
          if (g.mode == 0)      g.outA[idx] = f2bf(v);
          else if (g.mode == 1) { g.outA[idx] = f2bf((v + ba) * KQSC); g.outB[idx] = f2bf((v + bb) * KQSC); }
          else                  g.outF[idx] = v;
        }
      }
    }
  }
}

// ---------------- fused rel-attention per (b, h, 32-query tile) ----------------
// R9 structure: 512 threads = 8 waves, ~66 KiB LDS -> 2 WG/CU, k in 4 chunks
// of 512, wave wv owns k-share [wv*64, wv*64+64). One barrier per chunk.
//   A(c): R scatter, software-pipelined 1-deep (load jt+8 while computing jt)
//   pre-barrier: K-frags kt0/1 issued (latency under A + barrier wait)
//   B'(c): fully unrolled; kt2/3 issued at top; MFMA+exp2+cvt_pk, P in place
//   D(c): all 8 V-loads + 4 P-reads batched, then 16 MFMA under s_setprio
// Tail: cross-wave sum reduce, 8-way O reduce via reused score LDS.
__launch_bounds__(512, 4)
__global__ void attn_kernel(const unsigned short* __restrict__ qw,
                            const unsigned short* __restrict__ qr,
                            const unsigned short* __restrict__ kb,
                            const unsigned short* __restrict__ rb,
                            const unsigned short* __restrict__ vt,
                            unsigned short* __restrict__ xb) {
  __shared__ __align__(16) unsigned short sS[2][32 * SP2];  // dbuf score chunks
  __shared__ float sSum[8][32];
  __shared__ float sLinv[32];
  int bid = blockIdx.x;                 // 2048 = 32 bh * 64 qt
  int l = ((bid & 7) << 8) | (bid >> 3);  // XCD swizzle: xcd gets 4 whole bh
  int qt = l & 63;
  int bh = l >> 6;
  int b = bh >> 4, h = bh & 15;
  int q0 = qt * 32;
  int tid = threadIdx.x;
  int lane = tid & 63, wv = tid >> 6;   // wv 0..7
  int lm = lane & 15, lg = lane >> 4;

  // B-operand frags for Qw and Qr (pre-scaled by log2(e)/8 in GEMM):
  short8 bqw[2][2], bqr[2][2];
  const size_t qbase = (size_t)(b * S_ + q0) * HD_ + h * 64;
#pragma unroll
  for (int t = 0; t < 2; t++) {
    const unsigned short* p1 = qw + qbase + (size_t)(t * 16 + lm) * HD_ + lg * 8;
    const unsigned short* p2 = qr + qbase + (size_t)(t * 16 + lm) * HD_ + lg * 8;
    bqw[t][0] = *(const short8*)(p1);
    bqw[t][1] = *(const short8*)(p1 + 32);
    bqr[t][0] = *(const short8*)(p2);
    bqr[t][1] = *(const short8*)(p2 + 32);
  }

  floatx4 acc[2][4];                    // O accumulator (wave's k-share, all q,dh)
#pragma unroll
  for (int m = 0; m < 2; m++)
#pragma unroll
    for (int j = 0; j < 4; j++) acc[m][j] = (floatx4){0.f, 0.f, 0.f, 0.f};
  float s0 = 0.f, s1 = 0.f;             // exp-sum accumulators (t=0/1)

  const unsigned short* vb0 = vt + (size_t)(b * H_ + h) * 64 * S_;

  for (int c = 0; c < 4; c++) {
    unsigned short* S = sS[c & 1];
    int kc = c * KC_;

    // ---- A(c): R scatter, 1-deep pipelined over jt = wv, wv+8, ... < 34 ----
    auto rload = [&](int jt, short8& a0, short8& a1) {
      int jrow = (kc - q0 - 32 + jt * 16 + lm) & 2047;
      const unsigned short* rp = rb + (size_t)jrow * HD_ + h * 64 + lg * 8;
      a0 = *(const short8*)(rp);
      a1 = *(const short8*)(rp + 32);
    };
    auto rstore = [&](int jt, short8 a0, short8 a1) {
#pragma unroll
      for (int t = 0; t < 2; t++) {
        floatx4 c4 = (floatx4){0.f, 0.f, 0.f, 0.f};
        __builtin_amdgcn_s_setprio(1);
        c4 = __builtin_amdgcn_mfma_f32_16x16x32_bf16(a0, bqr[t][0], c4, 0, 0, 0);
        c4 = __builtin_amdgcn_mfma_f32_16x16x32_bf16(a1, bqr[t][1], c4, 0, 0, 0);
        __builtin_amdgcn_s_setprio(0);
        int q = t * 16 + lm;
        int ub = jt * 16 + lg * 4 + q - 31;   // u = k - kc for this lane's rows
        unsigned short* row = &S[q * SP2];
        if (jt + t >= 2 && jt + t <= 32) {    // wave-uniform: all 64 lanes in-range
#pragma unroll
          for (int r = 0; r < 4; r++) row[ub + r] = f2h(c4[r]);
        } else {
#pragma unroll
          for (int r = 0; r < 4; r++) {
            int u = ub + r;
            if ((unsigned)u < (unsigned)KC_) row[u] = f2h(c4[r]);
          }
        }
      }
    };
    {
      short8 ra0, ra1, rc0, rc1;
      rload(wv, ra0, ra1);
      rload(wv + 8, rc0, rc1);
      rstore(wv, ra0, ra1);
      rload(wv + 16, ra0, ra1);
      rstore(wv + 8, rc0, rc1);
      rload(wv + 24, rc0, rc1);
      rstore(wv + 16, ra0, ra1);
      if (wv < 2) {
        rload(wv + 32, ra0, ra1);
        rstore(wv + 24, rc0, rc1);
        rstore(wv + 32, ra0, ra1);
      } else {
        rstore(wv + 24, rc0, rc1);
      }
    }
    // ---- K prefetch kt0/1 BEFORE the barrier: latency hides under barrier ----
    const unsigned short* kp = kb + (size_t)(b * S_ + kc + wv * 64 + lm) * HD_ + h * 64 + lg * 8;
    short8 k0a = *(const short8*)(kp);
    short8 k0b = *(const short8*)(kp + 32);
    short8 k1a = *(const short8*)(kp + 16 * HD_);
    short8 k1b = *(const short8*)(kp + 16 * HD_ + 32);
    __syncthreads();                    // the only barrier in the chunk loop
    // ---- kt2/3 issued immediately; fly under kt0/1 compute ----
    short8 k2a = *(const short8*)(kp + 32 * HD_);
    short8 k2b = *(const short8*)(kp + 32 * HD_ + 32);
    short8 k3a = *(const short8*)(kp + 48 * HD_);
    short8 k3b = *(const short8*)(kp + 48 * HD_ + 32);

    // ---- B'(c): content + R + exp2 + sum + write P (bf16 via cvt_pk) ----
    auto bphase = [&](short8 a0, short8 a1, int kt) {
      int u0 = wv * 64 + kt * 16;
#pragma unroll
      for (int t = 0; t < 2; t++) {
        floatx4 c4 = (floatx4){0.f, 0.f, 0.f, 0.f};
        __builtin_amdgcn_s_setprio(1);
        c4 = __builtin_amdgcn_mfma_f32_16x16x32_bf16(a0, bqw[t][0], c4, 0, 0, 0);
        c4 = __builtin_amdgcn_mfma_f32_16x16x32_bf16(a1, bqw[t][1], c4, 0, 0, 0);
        __builtin_amdgcn_s_setprio(0);
        int q = t * 16 + lm;
        unsigned short* pp = &S[q * SP2 + u0 + lg * 4];
        ushort4 Rv = *(const ushort4*)pp;
        float p0 = exp2f(c4[0] + h2f(Rv.x));
        float p1 = exp2f(c4[1] + h2f(Rv.y));
        float p2 = exp2f(c4[2] + h2f(Rv.z));
        float p3 = exp2f(c4[3] + h2f(Rv.w));
        float ps = (p0 + p1) + (p2 + p3);
        if (t == 0) s0 += ps; else s1 += ps;
        unsigned w0, w1;
        asm("v_cvt_pk_bf16_f32 %0, %1, %2" : "=v"(w0) : "v"(p0), "v"(p1));
        asm("v_cvt_pk_bf16_f32 %0, %1, %2" : "=v"(w1) : "v"(p2), "v"(p3));
        *(uint2*)pp = make_uint2(w0, w1);
      }
    };
    bphase(k0a, k0b, 0);
    bphase(k1a, k1b, 1);
    bphase(k2a, k2b, 2);
    bphase(k3a, k3b, 3);

    // ---- D(c): batch 8 V-loads + 4 P-reads, then 16 MFMA under setprio ----
    {
      int u0 = wv * 64;
      const unsigned short* vp = vb0 + kc + u0 + lg * 8;
      short8 v0[4], v1[4];
#pragma unroll
      for (int j = 0; j < 4; j++) {
        v0[j] = *(const short8*)&vp[(size_t)(j * 16 + lm) * S_];
        v1[j] = *(const short8*)&vp[(size_t)(j * 16 + lm) * S_ + 32];
      }
      int e0 = lm * SP2 + u0 + lg * 8;
      int e1 = (16 + lm) * SP2 + u0 + lg * 8;
      uint2 x0 = *(const uint2*)&S[e0],      x1 = *(const uint2*)&S[e0 + 4];
      uint2 x2 = *(const uint2*)&S[e0 + 32], x3 = *(const uint2*)&S[e0 + 36];
      uint2 y0 = *(const uint2*)&S[e1],      y1 = *(const uint2*)&S[e1 + 4];
      uint2 y2 = *(const uint2*)&S[e1 + 32], y3 = *(const uint2*)&S[e1 + 36];
      uintx4 up00 = {x0.x, x0.y, x1.x, x1.y};
      uintx4 up01 = {y0.x, y0.y, y1.x, y1.y};
      uintx4 up10 = {x2.x, x2.y, x3.x, x3.y};
      uintx4 up11 = {y2.x, y2.y, y3.x, y3.y};
      short8 p00 = __builtin_bit_cast(short8, up00);   // q 0-15,  k-slice 0
      short8 p01 = __builtin_bit_cast(short8, up01);   // q 16-31, k-slice 0
      short8 p10 = __builtin_bit_cast(short8, up10);   // q 0-15,  k-slice 1
      short8 p11 = __builtin_bit_cast(short8, up11);   // q 16-31, k-slice 1
      __builtin_amdgcn_s_setprio(1);
#pragma unroll
      for (int j = 0; j < 4; j++) {
        acc[0][j] = __builtin_amdgcn_mfma_f32_16x16x32_bf16(p00, v0[j], acc[0][j], 0, 0, 0);
        acc[1][j] = __builtin_amdgcn_mfma_f32_16x16x32_bf16(p01, v0[j], acc[1][j], 0, 0, 0);
      }
#pragma unroll
      for (int j = 0; j < 4; j++) {
        acc[0][j] = __builtin_amdgcn_mfma_f32_16x16x32_bf16(p10, v1[j], acc[0][j], 0, 0, 0);
        acc[1][j] = __builtin_amdgcn_mfma_f32_16x16x32_bf16(p11, v1[j], acc[1][j], 0, 0, 0);
      }
      __builtin_amdgcn_s_setprio(0);
    }
  }
  // ---- tail: reduce exp-sums across lg (in-wave) then across waves ----
  s0 += __shfl_xor(s0, 16); s0 += __shfl_xor(s0, 32);
  s1 += __shfl_xor(s1, 16); s1 += __shfl_xor(s1, 32);
  if (lane < 16) { sSum[wv][lane] = s0; sSum[wv][16 + lane] = s1; }
  __syncthreads();                      // also: all D(3) P-reads done -> sS dead
  if (tid < 32) {
    float t = 0.f;
#pragma unroll
    for (int w = 0; w < 8; w++) t += sSum[w][tid];
    sLinv[tid] = 1.f / t;
  }
  float* po = (float*)sS;               // 8 waves x 2048 f32 = 64 KiB (fits dbuf)
#pragma unroll
  for (int m = 0; m < 2; m++)
#pragma unroll
    for (int j = 0; j < 4; j++)
#pragma unroll
      for (int r = 0; r < 4; r++) {
        int q = m * 16 + lg * 4 + r;
        int dh = j * 16 + lm;
        po[wv * 2048 + q * 64 + dh] = acc[m][j][r];
      }
  __syncthreads();
  {
    int e = tid * 4;                    // 512 threads x 4 = 2048 outputs
    int q = e >> 6, dh = e & 63;
    float4 v = *(float4*)&po[e];
#pragma unroll
    for (int w = 1; w < 8; w++) {
      float4 u = *(float4*)&po[w * 2048 + e];
      v.x += u.x; v.y += u.y; v.z += u.z; v.w += u.w;
    }
    float li = sLinv[q];
    ushort4 o = make_ushort4(f2bf(v.x * li), f2bf(v.y * li), f2bf(v.z * li), f2bf(v.w * li));
    *(ushort4*)&xb[(size_t)(b * S_ + q0 + q) * HD_ + h * 64 + dh] = o;
  }
}

extern "C" void kernel_launch(void* const* d_in, const int* in_sizes, int n_in,
                              void* d_out, int out_size, void* d_ws, size_t ws_size,
                              hipStream_t stream) {
  const float* inputs_q  = (const float*)d_in[0];
  const float* inputs_kv = (const float*)d_in[1];
  const float* pos_embed = (const float*)d_in[2];
  const float* Wq   = (const float*)d_in[3];
  const float* bq   = (const float*)d_in[4];
  const float* Wk   = (const float*)d_in[5];
  const float* bk   = (const float*)d_in[6];
  const float* Wv   = (const float*)d_in[7];
  const float* bv   = (const float*)d_in[8];
  const float* Wpos = (const float*)d_in[9];
  const float* rrb  = (const float*)d_in[10];
  const float* rwb  = (const float*)d_in[11];
  const float* Wout = (const float*)d_in[12];
  const float* bout = (const float*)d_in[13];
  float* out = (float*)d_out;

  char* ws = (char*)d_ws;                       // ~66 MB used
  unsigned short* aq  = (unsigned short*)(ws);                 // 8MB (reused as xb)
  unsigned short* akv = (unsigned short*)(ws + ( 8u << 20));   // 8MB
  unsigned short* apo = (unsigned short*)(ws + (16u << 20));   // 4MB
  unsigned short* wqt = (unsigned short*)(ws + (20u << 20));   // 2MB each
  unsigned short* wkt = (unsigned short*)(ws + (22u << 20));
  unsigned short* wvt = (unsigned short*)(ws + (24u << 20));
  unsigned short* wpt = (unsigned short*)(ws + (26u << 20));
  unsigned short* wot = (unsigned short*)(ws + (28u << 20));
  unsigned short* qwp = (unsigned short*)(ws + (30u << 20));   // 8MB
  unsigned short* qrp = (unsigned short*)(ws + (38u << 20));   // 8MB
  unsigned short* kbp = (unsigned short*)(ws + (46u << 20));   // 8MB
  unsigned short* vtp = (unsigned short*)(ws + (54u << 20));   // 8MB (vt layout)
  unsigned short* rbp = (unsigned short*)(ws + (62u << 20));   // 4MB
  unsigned short* xbp = aq;                                    // aq dead after q-GEMM

  PrepP pp;
  pp.sq = inputs_q; pp.skv = inputs_kv; pp.spos = pos_embed;
  pp.dq = aq; pp.dkv = akv; pp.dpos = apo;
  pp.ts[0] = Wq; pp.ts[1] = Wk; pp.ts[2] = Wv; pp.ts[3] = Wpos; pp.ts[4] = Wout;
  pp.td[0] = wqt; pp.td[1] = wkt; pp.td[2] = wvt; pp.td[3] = wpt; pp.td[4] = wot;
  prep_all<<<CAST_BLKS + 5120, 256, 0, stream>>>(pp);

  // all 4 projection GEMMs in ONE 896-block launch:
  //   [0,256): q dual-bias mode1 -> qwp/qrp   [256,384): rpos mode0 -> rbp
  //   [384,640): k mode0 -> kbp               [640,896): v mode4 -> vtp
  GP gp{};
  gp.s[0] = {aq,  wqt, bq,      rwb,     rrb,     qwp,     qrp,     nullptr, 1, 256};
  gp.s[1] = {apo, wpt, nullptr, nullptr, nullptr, rbp,     nullptr, nullptr, 0, 384};
  gp.s[2] = {akv, wkt, bk,      nullptr, nullptr, kbp,     nullptr, nullptr, 0, 640};
  gp.s[3] = {akv, wvt, bv,      nullptr, nullptr, vtp,     nullptr, nullptr, 4, 896};
  gemm_bt<<<896, 256, 0, stream>>>(gp, HD_, D_);

  attn_kernel<<<2048, 512, 0, stream>>>(qwp, qrp, kbp, rbp, vtp, xbp);

  GP go{};
  go.s[0] = {xbp, wot, bout, nullptr, nullptr, nullptr, nullptr, out, 2, 256};
  go.s[1] = {nullptr, nullptr, nullptr, nullptr, nullptr, nullptr, nullptr, nullptr, 0, 1 << 30};
  go.s[2] = go.s[1];
  go.s[3] = go.s[1];
  gemm_bt<<<256, 256, 0, stream>>>(go, F_, HD_);
}

// Round 6
// 505.397 us; speedup vs baseline: 1.2380x; 1.0702x over previous
//
#include <hip/hip_runtime.h>
#include <hip/hip_bf16.h>
#include <hip/hip_fp16.h>

// RelMultiHeadDotProductAttention (Transformer-XL rel attention)
// B=2 S=2048 D=1024 H=16 Dh=64 F=1024. fp32 in/out; internal bf16 MFMA.
// Round 12: occupancy via LDS, registers via time-sharing (R11 spilled again:
// +ILP under a 128-reg cap is impossible; R10 showed splitting work halves
// efficiency). Keep R9 phase structure/work-per-wave EXACTLY, but:
//  - single score buffer (34.2 KB LDS, was 66) -> LDS permits 4 WG/CU;
//    second barrier per chunk (D(c) -> A(c+1) now same buffer).
//  - Q time-share: reload Qr before A, Qw before B' (L1-hit, 8 b128/chunk);
//    asm memory clobber per phase stops LICM from keeping both sets live.
//  - __launch_bounds__(512,6): 84-reg cap -> 3 WG/CU; kt/s loops #pragma
//    unroll 1 so the unroller can't re-inflate pressure.
//  - tail two-pass O-reduce (po[4][2048] = 32 KB fits single buffer).
// Spill tripwire: WRITE_SIZE must stay ~8.2 MB.

#define B_  2
#define S_  2048
#define D_  1024
#define H_  16
#define DH_ 64
#define HD_ 1024
#define F_  1024
#define N_  4096   // B*S
#define KC_ 512    // k-chunk
#define SP2 516    // chunk row stride (fp16): 258 dw = 2 mod 32 banks
#define KQSC 0.1803368801111204f  // log2(e)/8, folded into qw/qr at GEMM epilogue

typedef __attribute__((ext_vector_type(8))) short  short8;   // 8 x bf16 (4 VGPRs)
typedef __attribute__((ext_vector_type(4))) float  floatx4;
typedef __attribute__((ext_vector_type(4))) unsigned int uintx4;

__device__ __forceinline__ unsigned short f2bf(float x) {
  unsigned u = __float_as_uint(x);
  u += 0x7FFFu + ((u >> 16) & 1u);          // RNE
  return (unsigned short)(u >> 16);
}
__device__ __forceinline__ unsigned short f2h(float x) {
  __half h = __float2half(x);
  unsigned short u; __builtin_memcpy(&u, &h, 2);
  return u;
}
__device__ __forceinline__ float h2f(unsigned short u) {
  __half h; __builtin_memcpy(&h, &u, 2);
  return __half2float(h);
}

// ------- prep: fp32->bf16 casts (q, kv, pos) + 5 weight transposes, ONE launch -------
#define CQ_ (N_ * D_ / 4)   // 1048576 float4 units each for q, kv
#define CAST_BLKS 10240     // (2*CQ_ + S_*D_/4) / 256
struct PrepP {
  const float* sq; const float* skv; const float* spos;
  unsigned short* dq; unsigned short* dkv; unsigned short* dpos;
  const float* ts[5]; unsigned short* td[5];
};
__global__ void prep_all(PrepP p) {
  __shared__ float t[32][33];
  int bid = blockIdx.x;
  int tid = threadIdx.x;
  if (bid < CAST_BLKS) {
    int i = bid * 256 + tid;
    const float* s; unsigned short* d; int off;
    if (i < CQ_)            { s = p.sq;   d = p.dq;   off = i; }
    else if (i < 2 * CQ_)   { s = p.skv;  d = p.dkv;  off = i - CQ_; }
    else                    { s = p.spos; d = p.dpos; off = i - 2 * CQ_; }
    float4 v = ((const float4*)s)[off];
    ((ushort4*)d)[off] = make_ushort4(f2bf(v.x), f2bf(v.y), f2bf(v.z), f2bf(v.w));
  } else {
    int b2 = bid - CAST_BLKS;               // 0..5119: 5 matrices x 32x32 tiles
    int z = b2 >> 10, y = (b2 >> 5) & 31, x = b2 & 31;
    const float* src = p.ts[z];
    unsigned short* dst = p.td[z];
    int c0 = x * 32, r0 = y * 32;
    int tx = tid & 31, ty = tid >> 5;       // (32,8)
#pragma unroll
    for (int i = 0; i < 4; i++)
      t[ty + i * 8][tx] = src[(size_t)(r0 + ty + i * 8) * 1024 + c0 + tx];
    __syncthreads();
#pragma unroll
    for (int i = 0; i < 4; i++)
      dst[(size_t)(c0 + ty + i * 8) * 1024 + r0 + tx] = f2bf(t[tx][ty + i * 8]);
  }
}

// ---------------- bf16 GEMM, C = A[M][K] * Bt[N][K]^T + bias ----------------
// 4-segment dispatch: block bx picks segment by bend boundaries (monotone).
// mode 0: outA bf16 = acc + bias
// mode 1: outA bf16 = (acc+bias+b2a)*KQSC ; outB bf16 = (acc+bias+b2b)*KQSC
// mode 2: outF fp32 = acc + bias
// mode 4: bf16, written directly in vt layout [b][h][dh][s]
struct GSeg {
  const unsigned short* A; const unsigned short* Bt;
  const float* bias; const float* b2a; const float* b2b;
  unsigned short* outA; unsigned short* outB; float* outF;
  int mode; int bend;
};
struct GP { GSeg s[4]; };
__launch_bounds__(256, 2)
__global__ void gemm_bt(GP p, int Nn, int K) {
  __shared__ unsigned short As[128 * 64];
  __shared__ unsigned short Bs[128 * 64];
  int bx = blockIdx.x;
  GSeg g = p.s[0]; int base = 0;
  if (bx >= p.s[0].bend) { g = p.s[1]; base = p.s[0].bend; }
  if (bx >= p.s[1].bend) { g = p.s[2]; base = p.s[1].bend; }
  if (bx >= p.s[2].bend) { g = p.s[3]; base = p.s[2].bend; }
  bx -= base;
  int nb = Nn >> 7;
  int bm = bx / nb, bn = bx % nb;
  int tid = threadIdx.x;
  int lane = tid & 63, wv = tid >> 6;
  int wm = wv >> 1, wn = wv & 1;
  int lm = lane & 15, lg = lane >> 4;
  const unsigned short* Ab = g.A + (size_t)(bm * 128) * K;
  const unsigned short* Bb = g.Bt + (size_t)(bn * 128) * K;
  floatx4 acc[4][4];
#pragma unroll
  for (int i = 0; i < 4; i++)
#pragma unroll
    for (int j = 0; j < 4; j++) acc[i][j] = (floatx4){0.f, 0.f, 0.f, 0.f};

  int lr = tid >> 3;          // 0..31 staging row
  int lc = (tid & 7) * 8;     // staging col (8 bf16 = 16B)
  for (int k0 = 0; k0 < K; k0 += 64) {
    __syncthreads();
#pragma unroll
    for (int i = 0; i < 4; i++) {
      int r = i * 32 + lr;
      *(uint4*)&As[r * 64 + lc] = *(const uint4*)&Ab[(size_t)r * K + k0 + lc];
      *(uint4*)&Bs[r * 64 + lc] = *(const uint4*)&Bb[(size_t)r * K + k0 + lc];
    }
    __syncthreads();
#pragma unroll
    for (int kk = 0; kk < 2; kk++) {
      short8 af[4], bf[4];
#pragma unroll
      for (int i = 0; i < 4; i++)
        af[i] = *(const short8*)&As[(wm * 64 + i * 16 + lm) * 64 + kk * 32 + lg * 8];
#pragma unroll
      for (int j = 0; j < 4; j++)
        bf[j] = *(const short8*)&Bs[(wn * 64 + j * 16 + lm) * 64 + kk * 32 + lg * 8];
#pragma unroll
      for (int i = 0; i < 4; i++)
#pragma unroll
        for (int j = 0; j < 4; j++)
          acc[i][j] = __builtin_amdgcn_mfma_f32_16x16x32_bf16(af[i], bf[j], acc[i][j], 0, 0, 0);
    }
  }
  // epilogue: C/D layout col=lane&15, row=(lane>>4)*4+reg  [m89/m91 verified]
#pragma unroll
  for (int j = 0; j < 4; j++) {
    int col = bn * 128 + wn * 64 + j * 16 + lm;
    float bs = g.bias ? g.bias[col] : 0.f;
    float ba = g.b2a ? g.b2a[col] : 0.f;
    float bb = g.b2b ? g.b2b[col] : 0.f;
#pragma unroll
    for (int i = 0; i < 4; i++) {
      int row0 = bm * 128 + wm * 64 + i * 16 + lg * 4;
      if (g.mode == 4) {
        // vt[b][h][dh][s]: 4 consecutive s -> vector store
        int s = row0 & 2047, bb2 = row0 >> 11;
        size_t vidx = (((size_t)bb2 * H_ + (col >> 6)) * 64 + (col & 63)) * (size_t)S_ + s;
        ushort4 o = make_ushort4(f2bf(acc[i][j][0] + bs), f2bf(acc[i][j][1] + bs),
                                 f2bf(acc[i][j][2] + bs), f2bf(acc[i][j][3] + bs));
        *(ushort4*)&g.outA[vidx] = o;
      } else {
#pragma unroll
        for (int r = 0; r < 4; r++) {
          float v = acc[i][j][r] + bs;
          size_t idx = (size_t)(row0 + r) * Nn + col;
          if (g.mode == 0)      g.outA[idx] = f2bf(v);
          else if (g.mode == 1) { g.outA[idx] = f2bf((v + ba) * KQSC); g.outB[idx] = f2bf((v + bb) * KQSC); }
          else                  g.outF[idx] = v;
        }
      }
    }
  }
}

// ---------------- fused rel-attention per (b, h, 32-query tile) ----------------
// R9 phases, single-buffered. 512 threads = 8 waves, 34.2 KiB LDS.
// Per chunk (4 chunks of 512): Qr reload -> A (R scatter) -> barrier ->
// Qw reload -> B' (content+R+exp2+sum+P in place) -> D (O += P V, own cols)
// -> barrier (buffer reuse). Tail: two-pass O reduce in the single buffer.
__launch_bounds__(512, 6)
__global__ void attn_kernel(const unsigned short* __restrict__ qw,
                            const unsigned short* __restrict__ qr,
                            const unsigned short* __restrict__ kb,
                            const unsigned short* __restrict__ rb,
                            const unsigned short* __restrict__ vt,
                            unsigned short* __restrict__ xb) {
  __shared__ __align__(16) unsigned short sS[32 * SP2];  // single score chunk (33 KB)
  __shared__ float sSum[8][32];
  __shared__ float sLinv[32];
  int bid = blockIdx.x;                 // 2048 = 32 bh * 64 qt
  int l = ((bid & 7) << 8) | (bid >> 3);  // XCD swizzle: xcd gets 4 whole bh
  int qt = l & 63;
  int bh = l >> 6;
  int b = bh >> 4, h = bh & 15;
  int q0 = qt * 32;
  int tid = threadIdx.x;
  int lane = tid & 63, wv = tid >> 6;   // wv 0..7
  int lm = lane & 15, lg = lane >> 4;

  floatx4 acc[2][4];                    // O accumulator (wave's k-share, all q,dh)
#pragma unroll
  for (int m = 0; m < 2; m++)
#pragma unroll
    for (int j = 0; j < 4; j++) acc[m][j] = (floatx4){0.f, 0.f, 0.f, 0.f};
  float s0 = 0.f, s1 = 0.f;             // exp-sum accumulators (t=0/1)

  const unsigned short* vb0 = vt + (size_t)(b * H_ + h) * 64 * S_;
  const size_t qfo = (size_t)(b * S_ + q0) * HD_ + h * 64;

  for (int c = 0; c < 4; c++) {
    int kc = c * KC_;
    // ---- Qr reload (time-shared regs; clobber keeps it inside the loop) ----
    asm volatile("" ::: "memory");
    short8 bq[2][2];
#pragma unroll
    for (int t = 0; t < 2; t++) {
      const unsigned short* p2 = qr + qfo + (size_t)(t * 16 + lm) * HD_ + lg * 8;
      bq[t][0] = *(const short8*)(p2);
      bq[t][1] = *(const short8*)(p2 + 32);
    }
    // ---- A(c): R scatter. j-window [kc-q0-32, kc-q0+511], 34 tiles of 16 ----
    for (int jt = wv; jt < 34; jt += 8) {
      int jrow = (kc - q0 - 32 + jt * 16 + lm) & 2047;
      const unsigned short* rp = rb + (size_t)jrow * HD_ + h * 64 + lg * 8;
      short8 a0 = *(const short8*)(rp);
      short8 a1 = *(const short8*)(rp + 32);
#pragma unroll
      for (int t = 0; t < 2; t++) {
        floatx4 c4 = (floatx4){0.f, 0.f, 0.f, 0.f};
        c4 = __builtin_amdgcn_mfma_f32_16x16x32_bf16(a0, bq[t][0], c4, 0, 0, 0);
        c4 = __builtin_amdgcn_mfma_f32_16x16x32_bf16(a1, bq[t][1], c4, 0, 0, 0);
        int q = t * 16 + lm;
        int ub = jt * 16 + lg * 4 + q - 31;   // u = k - kc for this lane's rows
        unsigned short* row = &sS[q * SP2];
        if (jt + t >= 2 && jt + t <= 32) {    // wave-uniform: all 64 lanes in-range
#pragma unroll
          for (int r = 0; r < 4; r++) row[ub + r] = f2h(c4[r]);
        } else {
#pragma unroll
          for (int r = 0; r < 4; r++) {
            int u = ub + r;
            if ((unsigned)u < (unsigned)KC_) row[u] = f2h(c4[r]);
          }
        }
      }
    }
    __syncthreads();                    // A writes visible to all waves
    // ---- Qw reload (Qr regs dead -> same storage) ----
    asm volatile("" ::: "memory");
#pragma unroll
    for (int t = 0; t < 2; t++) {
      const unsigned short* p1 = qw + qfo + (size_t)(t * 16 + lm) * HD_ + lg * 8;
      bq[t][0] = *(const short8*)(p1);
      bq[t][1] = *(const short8*)(p1 + 32);
    }
    // ---- B'(c): content + R + exp2 + sum + write P (bf16 via cvt_pk) ----
#pragma unroll 1
    for (int kt = 0; kt < 4; kt++) {
      int u0 = wv * 64 + kt * 16;
      const unsigned short* kp = kb + (size_t)(b * S_ + kc + u0 + lm) * HD_ + h * 64 + lg * 8;
      short8 a0 = *(const short8*)(kp);
      short8 a1 = *(const short8*)(kp + 32);
#pragma unroll
      for (int t = 0; t < 2; t++) {
        floatx4 c4 = (floatx4){0.f, 0.f, 0.f, 0.f};
        c4 = __builtin_amdgcn_mfma_f32_16x16x32_bf16(a0, bq[t][0], c4, 0, 0, 0);
        c4 = __builtin_amdgcn_mfma_f32_16x16x32_bf16(a1, bq[t][1], c4, 0, 0, 0);
        int q = t * 16 + lm;
        unsigned short* pp = &sS[q * SP2 + u0 + lg * 4];
        ushort4 Rv = *(const ushort4*)pp;
        float p0 = exp2f(c4[0] + h2f(Rv.x));
        float p1 = exp2f(c4[1] + h2f(Rv.y));
        float p2 = exp2f(c4[2] + h2f(Rv.z));
        float p3 = exp2f(c4[3] + h2f(Rv.w));
        float ps = (p0 + p1) + (p2 + p3);
        if (t == 0) s0 += ps; else s1 += ps;
        unsigned w0, w1;
        asm("v_cvt_pk_bf16_f32 %0, %1, %2" : "=v"(w0) : "v"(p0), "v"(p1));
        asm("v_cvt_pk_bf16_f32 %0, %1, %2" : "=v"(w1) : "v"(p2), "v"(p3));
        *(uint2*)pp = make_uint2(w0, w1);
      }
    }
    // ---- D(c): O += P V (own-wave P columns; same-wave program order) ----
#pragma unroll 1
    for (int s = 0; s < 2; s++) {
      int u0 = wv * 64 + s * 32;
      int e0 = lm * SP2 + u0 + lg * 8;
      int e1 = (16 + lm) * SP2 + u0 + lg * 8;
      uint2 x0 = *(const uint2*)&sS[e0];
      uint2 x1 = *(const uint2*)&sS[e0 + 4];
      uint2 y0 = *(const uint2*)&sS[e1];
      uint2 y1 = *(const uint2*)&sS[e1 + 4];
      uintx4 ua = {x0.x, x0.y, x1.x, x1.y};
      uintx4 ub = {y0.x, y0.y, y1.x, y1.y};
      short8 a0 = __builtin_bit_cast(short8, ua);
      short8 a1 = __builtin_bit_cast(short8, ub);
      const unsigned short* vp = vb0 + kc + u0 + lg * 8;
#pragma unroll
      for (int j = 0; j < 4; j++) {
        short8 bb = *(const short8*)&vp[(size_t)(j * 16 + lm) * S_];
        acc[0][j] = __builtin_amdgcn_mfma_f32_16x16x32_bf16(a0, bb, acc[0][j], 0, 0, 0);
        acc[1][j] = __builtin_amdgcn_mfma_f32_16x16x32_bf16(a1, bb, acc[1][j], 0, 0, 0);
      }
    }
    __syncthreads();                    // all D reads done before next A writes
  }
  // ---- tail: exp-sum reduce + two-pass O reduce in the single buffer ----
  s0 += __shfl_xor(s0, 16); s0 += __shfl_xor(s0, 32);
  s1 += __shfl_xor(s1, 16); s1 += __shfl_xor(s1, 32);
  if (lane < 16) { sSum[wv][lane] = s0; sSum[wv][16 + lane] = s1; }
  float* po = (float*)sS;               // 4 x 2048 f32 = 32 KiB (fits 33 KB buf)
  if (wv < 4) {
#pragma unroll
    for (int m = 0; m < 2; m++)
#pragma unroll
      for (int j = 0; j < 4; j++)
#pragma unroll
        for (int r = 0; r < 4; r++) {
          int q = m * 16 + lg * 4 + r;
          int dh = j * 16 + lm;
          po[wv * 2048 + q * 64 + dh] = acc[m][j][r];
        }
  }
  __syncthreads();
  if (tid < 32) {
    float t = 0.f;
#pragma unroll
    for (int w = 0; w < 8; w++) t += sSum[w][tid];
    sLinv[tid] = 1.f / t;
  }
  if (wv >= 4) {
#pragma unroll
    for (int m = 0; m < 2; m++)
#pragma unroll
      for (int j = 0; j < 4; j++)
#pragma unroll
        for (int r = 0; r < 4; r++) {
          int q = m * 16 + lg * 4 + r;
          int dh = j * 16 + lm;
          po[(wv - 4) * 2048 + q * 64 + dh] += acc[m][j][r];
        }
  }
  __syncthreads();
  {
    int e = tid * 4;                    // 512 threads x 4 = 2048 outputs
    int q = e >> 6, dh = e & 63;
    float4 v = *(float4*)&po[e];
#pragma unroll
    for (int i = 1; i < 4; i++) {
      float4 u = *(float4*)&po[i * 2048 + e];
      v.x += u.x; v.y += u.y; v.z += u.z; v.w += u.w;
    }
    float li = sLinv[q];
    ushort4 o = make_ushort4(f2bf(v.x * li), f2bf(v.y * li), f2bf(v.z * li), f2bf(v.w * li));
    *(ushort4*)&xb[(size_t)(b * S_ + q0 + q) * HD_ + h * 64 + dh] = o;
  }
}

extern "C" void kernel_launch(void* const* d_in, const int* in_sizes, int n_in,
                              void* d_out, int out_size, void* d_ws, size_t ws_size,
                              hipStream_t stream) {
  const float* inputs_q  = (const float*)d_in[0];
  const float* inputs_kv = (const float*)d_in[1];
  const float* pos_embed = (const float*)d_in[2];
  const float* Wq   = (const float*)d_in[3];
  const float* bq   = (const float*)d_in[4];
  const float* Wk   = (const float*)d_in[5];
  const float* bk   = (const float*)d_in[6];
  const float* Wv   = (const float*)d_in[7];
  const float* bv   = (const float*)d_in[8];
  const float* Wpos = (const float*)d_in[9];
  const float* rrb  = (const float*)d_in[10];
  const float* rwb  = (const float*)d_in[11];
  const float* Wout = (const float*)d_in[12];
  const float* bout = (const float*)d_in[13];
  float* out = (float*)d_out;

  char* ws = (char*)d_ws;                       // ~66 MB used
  unsigned short* aq  = (unsigned short*)(ws);                 // 8MB (reused as xb)
  unsigned short* akv = (unsigned short*)(ws + ( 8u << 20));   // 8MB
  unsigned short* apo = (unsigned short*)(ws + (16u << 20));   // 4MB
  unsigned short* wqt = (unsigned short*)(ws + (20u << 20));   // 2MB each
  unsigned short* wkt = (unsigned short*)(ws + (22u << 20));
  unsigned short* wvt = (unsigned short*)(ws + (24u << 20));
  unsigned short* wpt = (unsigned short*)(ws + (26u << 20));
  unsigned short* wot = (unsigned short*)(ws + (28u << 20));
  unsigned short* qwp = (unsigned short*)(ws + (30u << 20));   // 8MB
  unsigned short* qrp = (unsigned short*)(ws + (38u << 20));   // 8MB
  unsigned short* kbp = (unsigned short*)(ws + (46u << 20));   // 8MB
  unsigned short* vtp = (unsigned short*)(ws + (54u << 20));   // 8MB (vt layout)
  unsigned short* rbp = (unsigned short*)(ws + (62u << 20));   // 4MB
  unsigned short* xbp = aq;                                    // aq dead after q-GEMM

  PrepP pp;
  pp.sq = inputs_q; pp.skv = inputs_kv; pp.spos = pos_embed;
  pp.dq = aq; pp.dkv = akv; pp.dpos = apo;
  pp.ts[0] = Wq; pp.ts[1] = Wk; pp.ts[2] = Wv; pp.ts[3] = Wpos; pp.ts[4] = Wout;
  pp.td[0] = wqt; pp.td[1] = wkt; pp.td[2] = wvt; pp.td[3] = wpt; pp.td[4] = wot;
  prep_all<<<CAST_BLKS + 5120, 256, 0, stream>>>(pp);

  // all 4 projection GEMMs in ONE 896-block launch:
  //   [0,256): q dual-bias mode1 -> qwp/qrp   [256,384): rpos mode0 -> rbp
  //   [384,640): k mode0 -> kbp               [640,896): v mode4 -> vtp
  GP gp{};
  gp.s[0] = {aq,  wqt, bq,      rwb,     rrb,     qwp,     qrp,     nullptr, 1, 256};
  gp.s[1] = {apo, wpt, nullptr, nullptr, nullptr, rbp,     nullptr, nullptr, 0, 384};
  gp.s[2] = {akv, wkt, bk,      nullptr, nullptr, kbp,     nullptr, nullptr, 0, 640};
  gp.s[3] = {akv, wvt, bv,      nullptr, nullptr, vtp,     nullptr, nullptr, 4, 896};
  gemm_bt<<<896, 256, 0, stream>>>(gp, HD_, D_);

  attn_kernel<<<2048, 512, 0, stream>>>(qwp, qrp, kbp, rbp, vtp, xbp);

  GP go{};
  go.s[0] = {xbp, wot, bout, nullptr, nullptr, nullptr, nullptr, out, 2, 256};
  go.s[1] = {nullptr, nullptr, nullptr, nullptr, nullptr, nullptr, nullptr, nullptr, 0, 1 << 30};
  go.s[2] = go.s[1];
  go.s[3] = go.s[1];
  gemm_bt<<<256, 256, 0, stream>>>(go, F_, HD_);
}

// Round 7
// 409.690 us; speedup vs baseline: 1.5272x; 1.2336x over previous
//
#include <hip/hip_runtime.h>
#include <hip/hip_bf16.h>
#include <hip/hip_fp16.h>

// RelMultiHeadDotProductAttention (Transformer-XL rel attention)
// B=2 S=2048 D=1024 H=16 Dh=64 F=1024. fp32 in/out; internal bf16 MFMA.
// Round 13: occupancy via LDS ONLY — no register changes. R12 proved the
// occupancy direction (46->58% gave 349->313 even WITH spills) and proved the
// (512,6) cap causes the spills (VGPR_Count 40, 104MB scratch). R9's body is
// 64 VGPR under (512,4) -> register file already permits 8 waves/SIMD; its
// only cap was the 66KB LDS dbuf. So: R9 EXACT body (Qw/Qr resident, no
// time-share, no unroll pinning), single 33KB score buffer, second barrier
// per chunk (D reads -> next A writes), two-pass tail O-reduce (32KB fits).
// LDS 34.2KB -> 4 WG/CU. Spill tripwire: WRITE_SIZE must stay ~8.2MB.

#define B_  2
#define S_  2048
#define D_  1024
#define H_  16
#define DH_ 64
#define HD_ 1024
#define F_  1024
#define N_  4096   // B*S
#define KC_ 512    // k-chunk
#define SP2 516    // chunk row stride (fp16): 258 dw = 2 mod 32 banks
#define KQSC 0.1803368801111204f  // log2(e)/8, folded into qw/qr at GEMM epilogue

typedef __attribute__((ext_vector_type(8))) short  short8;   // 8 x bf16 (4 VGPRs)
typedef __attribute__((ext_vector_type(4))) float  floatx4;
typedef __attribute__((ext_vector_type(4))) unsigned int uintx4;

__device__ __forceinline__ unsigned short f2bf(float x) {
  unsigned u = __float_as_uint(x);
  u += 0x7FFFu + ((u >> 16) & 1u);          // RNE
  return (unsigned short)(u >> 16);
}
__device__ __forceinline__ unsigned short f2h(float x) {
  __half h = __float2half(x);
  unsigned short u; __builtin_memcpy(&u, &h, 2);
  return u;
}
__device__ __forceinline__ float h2f(unsigned short u) {
  __half h; __builtin_memcpy(&h, &u, 2);
  return __half2float(h);
}

// ------- prep: fp32->bf16 casts (q, kv, pos) + 5 weight transposes, ONE launch -------
#define CQ_ (N_ * D_ / 4)   // 1048576 float4 units each for q, kv
#define CAST_BLKS 10240     // (2*CQ_ + S_*D_/4) / 256
struct PrepP {
  const float* sq; const float* skv; const float* spos;
  unsigned short* dq; unsigned short* dkv; unsigned short* dpos;
  const float* ts[5]; unsigned short* td[5];
};
__global__ void prep_all(PrepP p) {
  __shared__ float t[32][33];
  int bid = blockIdx.x;
  int tid = threadIdx.x;
  if (bid < CAST_BLKS) {
    int i = bid * 256 + tid;
    const float* s; unsigned short* d; int off;
    if (i < CQ_)            { s = p.sq;   d = p.dq;   off = i; }
    else if (i < 2 * CQ_)   { s = p.skv;  d = p.dkv;  off = i - CQ_; }
    else                    { s = p.spos; d = p.dpos; off = i - 2 * CQ_; }
    float4 v = ((const float4*)s)[off];
    ((ushort4*)d)[off] = make_ushort4(f2bf(v.x), f2bf(v.y), f2bf(v.z), f2bf(v.w));
  } else {
    int b2 = bid - CAST_BLKS;               // 0..5119: 5 matrices x 32x32 tiles
    int z = b2 >> 10, y = (b2 >> 5) & 31, x = b2 & 31;
    const float* src = p.ts[z];
    unsigned short* dst = p.td[z];
    int c0 = x * 32, r0 = y * 32;
    int tx = tid & 31, ty = tid >> 5;       // (32,8)
#pragma unroll
    for (int i = 0; i < 4; i++)
      t[ty + i * 8][tx] = src[(size_t)(r0 + ty + i * 8) * 1024 + c0 + tx];
    __syncthreads();
#pragma unroll
    for (int i = 0; i < 4; i++)
      dst[(size_t)(c0 + ty + i * 8) * 1024 + r0 + tx] = f2bf(t[tx][ty + i * 8]);
  }
}

// ---------------- bf16 GEMM, C = A[M][K] * Bt[N][K]^T + bias ----------------
// 4-segment dispatch: block bx picks segment by bend boundaries (monotone).
// mode 0: outA bf16 = acc + bias
// mode 1: outA bf16 = (acc+bias+b2a)*KQSC ; outB bf16 = (acc+bias+b2b)*KQSC
// mode 2: outF fp32 = acc + bias
// mode 4: bf16, written directly in vt layout [b][h][dh][s]
struct GSeg {
  const unsigned short* A; const unsigned short* Bt;
  const float* bias; const float* b2a; const float* b2b;
  unsigned short* outA; unsigned short* outB; float* outF;
  int mode; int bend;
};
struct GP { GSeg s[4]; };
__launch_bounds__(256, 2)
__global__ void gemm_bt(GP p, int Nn, int K) {
  __shared__ unsigned short As[128 * 64];
  __shared__ unsigned short Bs[128 * 64];
  int bx = blockIdx.x;
  GSeg g = p.s[0]; int base = 0;
  if (bx >= p.s[0].bend) { g = p.s[1]; base = p.s[0].bend; }
  if (bx >= p.s[1].bend) { g = p.s[2]; base = p.s[1].bend; }
  if (bx >= p.s[2].bend) { g = p.s[3]; base = p.s[2].bend; }
  bx -= base;
  int nb = Nn >> 7;
  int bm = bx / nb, bn = bx % nb;
  int tid = threadIdx.x;
  int lane = tid & 63, wv = tid >> 6;
  int wm = wv >> 1, wn = wv & 1;
  int lm = lane & 15, lg = lane >> 4;
  const unsigned short* Ab = g.A + (size_t)(bm * 128) * K;
  const unsigned short* Bb = g.Bt + (size_t)(bn * 128) * K;
  floatx4 acc[4][4];
#pragma unroll
  for (int i = 0; i < 4; i++)
#pragma unroll
    for (int j = 0; j < 4; j++) acc[i][j] = (floatx4){0.f, 0.f, 0.f, 0.f};

  int lr = tid >> 3;          // 0..31 staging row
  int lc = (tid & 7) * 8;     // staging col (8 bf16 = 16B)
  for (int k0 = 0; k0 < K; k0 += 64) {
    __syncthreads();
#pragma unroll
    for (int i = 0; i < 4; i++) {
      int r = i * 32 + lr;
      *(uint4*)&As[r * 64 + lc] = *(const uint4*)&Ab[(size_t)r * K + k0 + lc];
      *(uint4*)&Bs[r * 64 + lc] = *(const uint4*)&Bb[(size_t)r * K + k0 + lc];
    }
    __syncthreads();
#pragma unroll
    for (int kk = 0; kk < 2; kk++) {
      short8 af[4], bf[4];
#pragma unroll
      for (int i = 0; i < 4; i++)
        af[i] = *(const short8*)&As[(wm * 64 + i * 16 + lm) * 64 + kk * 32 + lg * 8];
#pragma unroll
      for (int j = 0; j < 4; j++)
        bf[j] = *(const short8*)&Bs[(wn * 64 + j * 16 + lm) * 64 + kk * 32 + lg * 8];
#pragma unroll
      for (int i = 0; i < 4; i++)
#pragma unroll
        for (int j = 0; j < 4; j++)
          acc[i][j] = __builtin_amdgcn_mfma_f32_16x16x32_bf16(af[i], bf[j], acc[i][j], 0, 0, 0);
    }
  }
  // epilogue: C/D layout col=lane&15, row=(lane>>4)*4+reg  [m89/m91 verified]
#pragma unroll
  for (int j = 0; j < 4; j++) {
    int col = bn * 128 + wn * 64 + j * 16 + lm;
    float bs = g.bias ? g.bias[col] : 0.f;
    float ba = g.b2a ? g.b2a[col] : 0.f;
    float bb = g.b2b ? g.b2b[col] : 0.f;
#pragma unroll
    for (int i = 0; i < 4; i++) {
      int row0 = bm * 128 + wm * 64 + i * 16 + lg * 4;
      if (g.mode == 4) {
        // vt[b][h][dh][s]: 4 consecutive s -> vector store
        int s = row0 & 2047, bb2 = row0 >> 11;
        size_t vidx = (((size_t)bb2 * H_ + (col >> 6)) * 64 + (col & 63)) * (size_t)S_ + s;
        ushort4 o = make_ushort4(f2bf(acc[i][j][0] + bs), f2bf(acc[i][j][1] + bs),
                                 f2bf(acc[i][j][2] + bs), f2bf(acc[i][j][3] + bs));
        *(ushort4*)&g.outA[vidx] = o;
      } else {
#pragma unroll
        for (int r = 0; r < 4; r++) {
          float v = acc[i][j][r] + bs;
          size_t idx = (size_t)(row0 + r) * Nn + col;
          if (g.mode == 0)      g.outA[idx] = f2bf(v);
          else if (g.mode == 1) { g.outA[idx] = f2bf((v + ba) * KQSC); g.outB[idx] = f2bf((v + bb) * KQSC); }
          else                  g.outF[idx] = v;
        }
      }
    }
  }
}

// ---------------- fused rel-attention per (b, h, 32-query tile) ----------------
// R9 body, single-buffered: 512 threads = 8 waves, 34.2 KiB LDS -> 4 WG/CU
// (regs: 64 VGPR -> 8 waves/SIMD permitted; LDS is the only cap now).
// Per chunk (4 chunks of 512), wave wv owns k-share [wv*64, wv*64+64):
//   A(c): R^T = rpos . Qr^T, scatter fp16 into score chunk (uniform fast path)
//   barrier; B'(c): K.Qw^T + R + exp2 + sum (regs), P bf16 in place (cvt_pk)
//   D(c): O += P V (own-wave P cols, same-wave program order, no barrier)
//   barrier (all D reads done before next chunk's A overwrites the buffer)
// Tail: cross-wave sum reduce; two-pass 8->4->1 O reduce (32 KB fits buffer).
__launch_bounds__(512, 4)
__global__ void attn_kernel(const unsigned short* __restrict__ qw,
                            const unsigned short* __restrict__ qr,
                            const unsigned short* __restrict__ kb,
                            const unsigned short* __restrict__ rb,
                            const unsigned short* __restrict__ vt,
                            unsigned short* __restrict__ xb) {
  __shared__ __align__(16) unsigned short sS[32 * SP2];  // single score chunk (33 KB)
  __shared__ float sSum[8][32];
  __shared__ float sLinv[32];
  int bid = blockIdx.x;                 // 2048 = 32 bh * 64 qt
  int l = ((bid & 7) << 8) | (bid >> 3);  // XCD swizzle: xcd gets 4 whole bh
  int qt = l & 63;
  int bh = l >> 6;
  int b = bh >> 4, h = bh & 15;
  int q0 = qt * 32;
  int tid = threadIdx.x;
  int lane = tid & 63, wv = tid >> 6;   // wv 0..7
  int lm = lane & 15, lg = lane >> 4;

  // B-operand frags for Qw and Qr (pre-scaled by log2(e)/8 in GEMM):
  // B[n=lane&15][k=(lane>>4)*8+j]; 2 q-halves x 2 k-halves
  short8 bqw[2][2], bqr[2][2];
  const size_t qbase = (size_t)(b * S_ + q0) * HD_ + h * 64;
#pragma unroll
  for (int t = 0; t < 2; t++) {
    const unsigned short* p1 = qw + qbase + (size_t)(t * 16 + lm) * HD_ + lg * 8;
    const unsigned short* p2 = qr + qbase + (size_t)(t * 16 + lm) * HD_ + lg * 8;
    bqw[t][0] = *(const short8*)(p1);
    bqw[t][1] = *(const short8*)(p1 + 32);
    bqr[t][0] = *(const short8*)(p2);
    bqr[t][1] = *(const short8*)(p2 + 32);
  }

  floatx4 acc[2][4];                    // O accumulator (wave's k-share, all q,dh)
#pragma unroll
  for (int m = 0; m < 2; m++)
#pragma unroll
    for (int j = 0; j < 4; j++) acc[m][j] = (floatx4){0.f, 0.f, 0.f, 0.f};
  float s0 = 0.f, s1 = 0.f;             // exp-sum accumulators (t=0/1)

  const unsigned short* vb0 = vt + (size_t)(b * H_ + h) * 64 * S_;

  for (int c = 0; c < 4; c++) {
    unsigned short* S = sS;
    int kc = c * KC_;
    // ---- A(c): R scatter. j-window [kc-q0-32, kc-q0+511], 34 tiles of 16 ----
    for (int jt = wv; jt < 34; jt += 8) {
      int jrow = (kc - q0 - 32 + jt * 16 + lm) & 2047;
      const unsigned short* rp = rb + (size_t)jrow * HD_ + h * 64 + lg * 8;
      short8 a0 = *(const short8*)(rp);
      short8 a1 = *(const short8*)(rp + 32);
#pragma unroll
      for (int t = 0; t < 2; t++) {
        floatx4 c4 = (floatx4){0.f, 0.f, 0.f, 0.f};
        c4 = __builtin_amdgcn_mfma_f32_16x16x32_bf16(a0, bqr[t][0], c4, 0, 0, 0);
        c4 = __builtin_amdgcn_mfma_f32_16x16x32_bf16(a1, bqr[t][1], c4, 0, 0, 0);
        int q = t * 16 + lm;
        int ub = jt * 16 + lg * 4 + q - 31;   // u = k - kc for this lane's rows
        unsigned short* row = &S[q * SP2];
        if (jt + t >= 2 && jt + t <= 32) {    // wave-uniform: all 64 lanes in-range
#pragma unroll
          for (int r = 0; r < 4; r++) row[ub + r] = f2h(c4[r]);
        } else {
#pragma unroll
          for (int r = 0; r < 4; r++) {
            int u = ub + r;
            if ((unsigned)u < (unsigned)KC_) row[u] = f2h(c4[r]);
          }
        }
      }
    }
    __syncthreads();                    // A writes visible to all waves
    // ---- B'(c): content + R + exp2 + sum + write P (bf16 via cvt_pk) ----
#pragma unroll 2
    for (int kt = 0; kt < 4; kt++) {
      int u0 = wv * 64 + kt * 16;
      const unsigned short* kp = kb + (size_t)(b * S_ + kc + u0 + lm) * HD_ + h * 64 + lg * 8;
      short8 a0 = *(const short8*)(kp);
      short8 a1 = *(const short8*)(kp + 32);
#pragma unroll
      for (int t = 0; t < 2; t++) {
        floatx4 c4 = (floatx4){0.f, 0.f, 0.f, 0.f};
        c4 = __builtin_amdgcn_mfma_f32_16x16x32_bf16(a0, bqw[t][0], c4, 0, 0, 0);
        c4 = __builtin_amdgcn_mfma_f32_16x16x32_bf16(a1, bqw[t][1], c4, 0, 0, 0);
        int q = t * 16 + lm;
        unsigned short* pp = &S[q * SP2 + u0 + lg * 4];
        ushort4 Rv = *(const ushort4*)pp;
        float p0 = exp2f(c4[0] + h2f(Rv.x));
        float p1 = exp2f(c4[1] + h2f(Rv.y));
        float p2 = exp2f(c4[2] + h2f(Rv.z));
        float p3 = exp2f(c4[3] + h2f(Rv.w));
        float ps = (p0 + p1) + (p2 + p3);
        if (t == 0) s0 += ps; else s1 += ps;
        unsigned w0, w1;
        asm("v_cvt_pk_bf16_f32 %0, %1, %2" : "=v"(w0) : "v"(p0), "v"(p1));
        asm("v_cvt_pk_bf16_f32 %0, %1, %2" : "=v"(w1) : "v"(p2), "v"(p3));
        *(uint2*)pp = make_uint2(w0, w1);
      }
    }
    // ---- D(c): O += P V (own-wave P columns; same-wave program order).
    //      P reads as 2x b64: dw-stride 258 = 2 mod 32 -> uniform banks. ----
#pragma unroll
    for (int s = 0; s < 2; s++) {
      int u0 = wv * 64 + s * 32;
      int e0 = lm * SP2 + u0 + lg * 8;
      int e1 = (16 + lm) * SP2 + u0 + lg * 8;
      uint2 x0 = *(const uint2*)&S[e0];
      uint2 x1 = *(const uint2*)&S[e0 + 4];
      uint2 y0 = *(const uint2*)&S[e1];
      uint2 y1 = *(const uint2*)&S[e1 + 4];
      uintx4 ua = {x0.x, x0.y, x1.x, x1.y};
      uintx4 ub = {y0.x, y0.y, y1.x, y1.y};
      short8 a0 = __builtin_bit_cast(short8, ua);
      short8 a1 = __builtin_bit_cast(short8, ub);
      const unsigned short* vp = vb0 + kc + u0 + lg * 8;
#pragma unroll
      for (int j = 0; j < 4; j++) {
        short8 bb = *(const short8*)&vp[(size_t)(j * 16 + lm) * S_];
        acc[0][j] = __builtin_amdgcn_mfma_f32_16x16x32_bf16(a0, bb, acc[0][j], 0, 0, 0);
        acc[1][j] = __builtin_amdgcn_mfma_f32_16x16x32_bf16(a1, bb, acc[1][j], 0, 0, 0);
      }
    }
    __syncthreads();                    // all D reads done before next A writes
  }
  // ---- tail: exp-sum reduce + two-pass O reduce in the single buffer ----
  s0 += __shfl_xor(s0, 16); s0 += __shfl_xor(s0, 32);
  s1 += __shfl_xor(s1, 16); s1 += __shfl_xor(s1, 32);
  if (lane < 16) { sSum[wv][lane] = s0; sSum[wv][16 + lane] = s1; }
  float* po = (float*)sS;               // 4 x 2048 f32 = 32 KiB (fits 33 KB buf)
  if (wv < 4) {
#pragma unroll
    for (int m = 0; m < 2; m++)
#pragma unroll
      for (int j = 0; j < 4; j++)
#pragma unroll
        for (int r = 0; r < 4; r++) {
          int q = m * 16 + lg * 4 + r;
          int dh = j * 16 + lm;
          po[wv * 2048 + q * 64 + dh] = acc[m][j][r];
        }
  }
  __syncthreads();
  if (tid < 32) {
    float t = 0.f;
#pragma unroll
    for (int w = 0; w < 8; w++) t += sSum[w][tid];
    sLinv[tid] = 1.f / t;
  }
  if (wv >= 4) {
#pragma unroll
    for (int m = 0; m < 2; m++)
#pragma unroll
      for (int j = 0; j < 4; j++)
#pragma unroll
        for (int r = 0; r < 4; r++) {
          int q = m * 16 + lg * 4 + r;
          int dh = j * 16 + lm;
          po[(wv - 4) * 2048 + q * 64 + dh] += acc[m][j][r];
        }
  }
  __syncthreads();
  {
    int e = tid * 4;                    // 512 threads x 4 = 2048 outputs
    int q = e >> 6, dh = e & 63;
    float4 v = *(float4*)&po[e];
#pragma unroll
    for (int i = 1; i < 4; i++) {
      float4 u = *(float4*)&po[i * 2048 + e];
      v.x += u.x; v.y += u.y; v.z += u.z; v.w += u.w;
    }
    float li = sLinv[q];
    ushort4 o = make_ushort4(f2bf(v.x * li), f2bf(v.y * li), f2bf(v.z * li), f2bf(v.w * li));
    *(ushort4*)&xb[(size_t)(b * S_ + q0 + q) * HD_ + h * 64 + dh] = o;
  }
}

extern "C" void kernel_launch(void* const* d_in, const int* in_sizes, int n_in,
                              void* d_out, int out_size, void* d_ws, size_t ws_size,
                              hipStream_t stream) {
  const float* inputs_q  = (const float*)d_in[0];
  const float* inputs_kv = (const float*)d_in[1];
  const float* pos_embed = (const float*)d_in[2];
  const float* Wq   = (const float*)d_in[3];
  const float* bq   = (const float*)d_in[4];
  const float* Wk   = (const float*)d_in[5];
  const float* bk   = (const float*)d_in[6];
  const float* Wv   = (const float*)d_in[7];
  const float* bv   = (const float*)d_in[8];
  const float* Wpos = (const float*)d_in[9];
  const float* rrb  = (const float*)d_in[10];
  const float* rwb  = (const float*)d_in[11];
  const float* Wout = (const float*)d_in[12];
  const float* bout = (const float*)d_in[13];
  float* out = (float*)d_out;

  char* ws = (char*)d_ws;                       // ~66 MB used
  unsigned short* aq  = (unsigned short*)(ws);                 // 8MB (reused as xb)
  unsigned short* akv = (unsigned short*)(ws + ( 8u << 20));   // 8MB
  unsigned short* apo = (unsigned short*)(ws + (16u << 20));   // 4MB
  unsigned short* wqt = (unsigned short*)(ws + (20u << 20));   // 2MB each
  unsigned short* wkt = (unsigned short*)(ws + (22u << 20));
  unsigned short* wvt = (unsigned short*)(ws + (24u << 20));
  unsigned short* wpt = (unsigned short*)(ws + (26u << 20));
  unsigned short* wot = (unsigned short*)(ws + (28u << 20));
  unsigned short* qwp = (unsigned short*)(ws + (30u << 20));   // 8MB
  unsigned short* qrp = (unsigned short*)(ws + (38u << 20));   // 8MB
  unsigned short* kbp = (unsigned short*)(ws + (46u << 20));   // 8MB
  unsigned short* vtp = (unsigned short*)(ws + (54u << 20));   // 8MB (vt layout)
  unsigned short* rbp = (unsigned short*)(ws + (62u << 20));   // 4MB
  unsigned short* xbp = aq;                                    // aq dead after q-GEMM

  PrepP pp;
  pp.sq = inputs_q; pp.skv = inputs_kv; pp.spos = pos_embed;
  pp.dq = aq; pp.dkv = akv; pp.dpos = apo;
  pp.ts[0] = Wq; pp.ts[1] = Wk; pp.ts[2] = Wv; pp.ts[3] = Wpos; pp.ts[4] = Wout;
  pp.td[0] = wqt; pp.td[1] = wkt; pp.td[2] = wvt; pp.td[3] = wpt; pp.td[4] = wot;
  prep_all<<<CAST_BLKS + 5120, 256, 0, stream>>>(pp);

  // all 4 projection GEMMs in ONE 896-block launch:
  //   [0,256): q dual-bias mode1 -> qwp/qrp   [256,384): rpos mode0 -> rbp
  //   [384,640): k mode0 -> kbp               [640,896): v mode4 -> vtp
  GP gp{};
  gp.s[0] = {aq,  wqt, bq,      rwb,     rrb,     qwp,     qrp,     nullptr, 1, 256};
  gp.s[1] = {apo, wpt, nullptr, nullptr, nullptr, rbp,     nullptr, nullptr, 0, 384};
  gp.s[2] = {akv, wkt, bk,      nullptr, nullptr, kbp,     nullptr, nullptr, 0, 640};
  gp.s[3] = {akv, wvt, bv,      nullptr, nullptr, vtp,     nullptr, nullptr, 4, 896};
  gemm_bt<<<896, 256, 0, stream>>>(gp, HD_, D_);

  attn_kernel<<<2048, 512, 0, stream>>>(qwp, qrp, kbp, rbp, vtp, xbp);

  GP go{};
  go.s[0] = {xbp, wot, bout, nullptr, nullptr, nullptr, nullptr, out, 2, 256};
  go.s[1] = {nullptr, nullptr, nullptr, nullptr, nullptr, nullptr, nullptr, nullptr, 0, 1 << 30};
  go.s[2] = go.s[1];
  go.s[3] = go.s[1];
  gemm_bt<<<256, 256, 0, stream>>>(go, F_, HD_);
}